// Round 1
// baseline (62.062 us; speedup 1.0000x reference)
//
#include <hip/hip_runtime.h>

#define POOL 7
#define FM_H 128
#define FM_W 128
#define FM_C 512

// One cell = (roi r, pooled y, pooled x) -> 512 contiguous fp32 channels.
// 128 lanes x float4 = 512 channels per cell; 2 cells per 256-thread block.
__global__ __launch_bounds__(256) void roi_pool_kernel(
    const float* __restrict__ fm,    // [128,128,512] NHWC (batch 1)
    const float* __restrict__ rois,  // [R,4] = xmin,xmax,ymin,ymax (integral floats)
    float* __restrict__ out,         // [R,7,7,512]
    int n_cells)                     // R*49
{
    const int tid  = threadIdx.x;
    const int cell = blockIdx.x * 2 + (tid >> 7);   // 2 cells per block
    if (cell >= n_cells) return;
    const int c4   = (tid & 127) << 2;              // channel offset (x4 floats)

    const int r  = cell / (POOL * POOL);
    const int p  = cell - r * (POOL * POOL);
    const int py = p / POOL;
    const int px = p - py * POOL;

    // rois are integral values stored as f32; astype(int32) == truncation.
    const float4 rv = *reinterpret_cast<const float4*>(rois + (size_t)r * 4);
    const int xmin = (int)rv.x;
    const int xmax = (int)rv.y;
    const int ymin = (int)rv.z;
    const int ymax = (int)rv.w;
    const int sy = ymax - ymin;
    const int sx = xmax - xmin;

    // _axis_coords, replicated op-for-op in fp32 to match the reference.
    const float scy  = (float)sy / 7.0f;
    const float srcy = (float)py * scy;
    const int   iy0  = (int)floorf(srcy);
    const int   iy1  = min(iy0 + 1, sy - 1);
    const float fy   = srcy - (float)iy0;
    const int   y0   = ymin + iy0;
    const int   y1   = ymin + iy1;

    const float scx  = (float)sx / 7.0f;
    const float srcx = (float)px * scx;
    const int   ix0  = (int)floorf(srcx);
    const int   ix1  = min(ix0 + 1, sx - 1);
    const float fx   = srcx - (float)ix0;
    const int   x0   = xmin + ix0;
    const int   x1   = xmin + ix1;

    const size_t o00 = ((size_t)(y0 * FM_W + x0)) * FM_C + c4;
    const size_t o01 = ((size_t)(y0 * FM_W + x1)) * FM_C + c4;
    const size_t o10 = ((size_t)(y1 * FM_W + x0)) * FM_C + c4;
    const size_t o11 = ((size_t)(y1 * FM_W + x1)) * FM_C + c4;

    const float4 tl = *reinterpret_cast<const float4*>(fm + o00);
    const float4 tr = *reinterpret_cast<const float4*>(fm + o01);
    const float4 bl = *reinterpret_cast<const float4*>(fm + o10);
    const float4 br = *reinterpret_cast<const float4*>(fm + o11);

    float4 o;
    {
        float top, bot;
        top = tl.x + (tr.x - tl.x) * fx; bot = bl.x + (br.x - bl.x) * fx; o.x = top + (bot - top) * fy;
        top = tl.y + (tr.y - tl.y) * fx; bot = bl.y + (br.y - bl.y) * fx; o.y = top + (bot - top) * fy;
        top = tl.z + (tr.z - tl.z) * fx; bot = bl.z + (br.z - bl.z) * fx; o.z = top + (bot - top) * fy;
        top = tl.w + (tr.w - tl.w) * fx; bot = bl.w + (br.w - bl.w) * fx; o.w = top + (bot - top) * fy;
    }

    *reinterpret_cast<float4*>(out + (size_t)cell * FM_C + c4) = o;
}

extern "C" void kernel_launch(void* const* d_in, const int* in_sizes, int n_in,
                              void* d_out, int out_size, void* d_ws, size_t ws_size,
                              hipStream_t stream) {
    const float* fm   = (const float*)d_in[0];
    const float* rois = (const float*)d_in[1];
    float* out        = (float*)d_out;

    const int R       = in_sizes[1] / 4;
    const int n_cells = R * POOL * POOL;          // 1024*49 = 50176
    const int blocks  = (n_cells + 1) / 2;        // 2 cells per block

    roi_pool_kernel<<<blocks, 256, 0, stream>>>(fm, rois, out, n_cells);
}

// Round 3
// 60.025 us; speedup vs baseline: 1.0339x; 1.0339x over previous
//
#include <hip/hip_runtime.h>

#define POOL 7
#define FM_H 128
#define FM_W 128
#define FM_C 512

typedef float f32x4 __attribute__((ext_vector_type(4)));  // native vector for nontemporal builtin

// One cell = (roi r, pooled y, pooled x) -> 512 contiguous fp32 channels.
// 128 lanes x float4 = 512 channels per cell; 2 cells per 256-thread block.
// Output stores are nontemporal: write-once data must not thrash the 4 MiB/XCD
// L2 that feature-map rows need (R1: FETCH=151MB vs 33.5MB fm).
__global__ __launch_bounds__(256) void roi_pool_kernel(
    const float* __restrict__ fm,    // [128,128,512] NHWC (batch 1)
    const float* __restrict__ rois,  // [R,4] = xmin,xmax,ymin,ymax (integral floats)
    float* __restrict__ out,         // [R,7,7,512]
    int n_cells)                     // R*49
{
    const int tid  = threadIdx.x;
    const int cell = blockIdx.x * 2 + (tid >> 7);   // 2 cells per block
    if (cell >= n_cells) return;
    const int c4   = (tid & 127) << 2;              // channel offset (x4 floats)

    const int r  = cell / (POOL * POOL);
    const int p  = cell - r * (POOL * POOL);
    const int py = p / POOL;
    const int px = p - py * POOL;

    // rois are integral values stored as f32; astype(int32) == truncation.
    const float4 rv = *reinterpret_cast<const float4*>(rois + (size_t)r * 4);
    const int xmin = (int)rv.x;
    const int xmax = (int)rv.y;
    const int ymin = (int)rv.z;
    const int ymax = (int)rv.w;
    const int sy = ymax - ymin;
    const int sx = xmax - xmin;

    // _axis_coords, replicated op-for-op in fp32 to match the reference.
    const float scy  = (float)sy / 7.0f;
    const float srcy = (float)py * scy;
    const int   iy0  = (int)floorf(srcy);
    const int   iy1  = min(iy0 + 1, sy - 1);
    const float fy   = srcy - (float)iy0;
    const int   y0   = ymin + iy0;
    const int   y1   = ymin + iy1;

    const float scx  = (float)sx / 7.0f;
    const float srcx = (float)px * scx;
    const int   ix0  = (int)floorf(srcx);
    const int   ix1  = min(ix0 + 1, sx - 1);
    const float fx   = srcx - (float)ix0;
    const int   x0   = xmin + ix0;
    const int   x1   = xmin + ix1;

    const size_t o00 = ((size_t)(y0 * FM_W + x0)) * FM_C + c4;
    const size_t o01 = ((size_t)(y0 * FM_W + x1)) * FM_C + c4;
    const size_t o10 = ((size_t)(y1 * FM_W + x0)) * FM_C + c4;
    const size_t o11 = ((size_t)(y1 * FM_W + x1)) * FM_C + c4;

    const float4 tl = *reinterpret_cast<const float4*>(fm + o00);
    const float4 tr = *reinterpret_cast<const float4*>(fm + o01);
    const float4 bl = *reinterpret_cast<const float4*>(fm + o10);
    const float4 br = *reinterpret_cast<const float4*>(fm + o11);

    f32x4 o;
    {
        float top, bot;
        top = tl.x + (tr.x - tl.x) * fx; bot = bl.x + (br.x - bl.x) * fx; o.x = top + (bot - top) * fy;
        top = tl.y + (tr.y - tl.y) * fx; bot = bl.y + (br.y - bl.y) * fx; o.y = top + (bot - top) * fy;
        top = tl.z + (tr.z - tl.z) * fx; bot = bl.z + (br.z - bl.z) * fx; o.z = top + (bot - top) * fy;
        top = tl.w + (tr.w - tl.w) * fx; bot = bl.w + (br.w - bl.w) * fx; o.w = top + (bot - top) * fy;
    }

    // Nontemporal streaming store — bypass/deprioritize L2 allocation.
    f32x4* dst = reinterpret_cast<f32x4*>(out + (size_t)cell * FM_C + c4);
    __builtin_nontemporal_store(o, dst);
}

extern "C" void kernel_launch(void* const* d_in, const int* in_sizes, int n_in,
                              void* d_out, int out_size, void* d_ws, size_t ws_size,
                              hipStream_t stream) {
    const float* fm   = (const float*)d_in[0];
    const float* rois = (const float*)d_in[1];
    float* out        = (float*)d_out;

    const int R       = in_sizes[1] / 4;
    const int n_cells = R * POOL * POOL;          // 1024*49 = 50176
    const int blocks  = (n_cells + 1) / 2;        // 2 cells per block

    roi_pool_kernel<<<blocks, 256, 0, stream>>>(fm, rois, out, n_cells);
}

// Round 4
// 27.490 us; speedup vs baseline: 2.2576x; 2.1835x over previous
//
#include <hip/hip_runtime.h>

#define POOL 7
#define FM_H 128
#define FM_W 128
#define FM_C 512
#define NGRP 8                 // channel groups == XCD count
#define GRP_C (FM_C / NGRP)    // 64 channels per group -> 4 MiB fm slice = 1 XCD L2
#define CELLS_PER_BLK 16       // 256 threads = 16 cells x 16 lanes x float4

typedef float f32x4 __attribute__((ext_vector_type(4)));

// Channel-partitioned ROI pooling. Group g = blockIdx.x % 8 -> lands on XCD g
// (empirical round-robin dispatch), so each XCD only ever touches its own
// 4 MiB channel slice of the feature map -> no cross-XCD L2 duplication
// (R3: FETCH was 145 MB vs 33.5 MB fm = 4.3x duplication).
__global__ __launch_bounds__(256) void roi_pool_kernel(
    const float* __restrict__ fm,    // [128,128,512] NHWC (batch 1)
    const float* __restrict__ rois,  // [R,4] = xmin,xmax,ymin,ymax (integral floats)
    float* __restrict__ out,         // [R,7,7,512]
    int n_cells)                     // R*49
{
    const int tid  = threadIdx.x;
    const int g    = blockIdx.x & (NGRP - 1);        // channel group -> XCD
    const int cb   = blockIdx.x >> 3;
    const int cell = cb * CELLS_PER_BLK + (tid >> 4);
    if (cell >= n_cells) return;
    const int c4   = (g << 6) + ((tid & 15) << 2);   // g*64 + lane16*4

    const int r  = cell / (POOL * POOL);
    const int p  = cell - r * (POOL * POOL);
    const int py = p / POOL;
    const int px = p - py * POOL;

    // rois are integral values stored as f32; astype(int32) == truncation.
    const float4 rv = *reinterpret_cast<const float4*>(rois + (size_t)r * 4);
    const int xmin = (int)rv.x;
    const int xmax = (int)rv.y;
    const int ymin = (int)rv.z;
    const int ymax = (int)rv.w;
    const int sy = ymax - ymin;
    const int sx = xmax - xmin;

    // _axis_coords, replicated op-for-op in fp32 to match the reference.
    const float scy  = (float)sy / 7.0f;
    const float srcy = (float)py * scy;
    const int   iy0  = (int)floorf(srcy);
    const int   iy1  = min(iy0 + 1, sy - 1);
    const float fy   = srcy - (float)iy0;
    const int   y0   = ymin + iy0;
    const int   y1   = ymin + iy1;

    const float scx  = (float)sx / 7.0f;
    const float srcx = (float)px * scx;
    const int   ix0  = (int)floorf(srcx);
    const int   ix1  = min(ix0 + 1, sx - 1);
    const float fx   = srcx - (float)ix0;
    const int   x0   = xmin + ix0;
    const int   x1   = xmin + ix1;

    const size_t o00 = ((size_t)(y0 * FM_W + x0)) * FM_C + c4;
    const size_t o01 = ((size_t)(y0 * FM_W + x1)) * FM_C + c4;
    const size_t o10 = ((size_t)(y1 * FM_W + x0)) * FM_C + c4;
    const size_t o11 = ((size_t)(y1 * FM_W + x1)) * FM_C + c4;

    const float4 tl = *reinterpret_cast<const float4*>(fm + o00);
    const float4 tr = *reinterpret_cast<const float4*>(fm + o01);
    const float4 bl = *reinterpret_cast<const float4*>(fm + o10);
    const float4 br = *reinterpret_cast<const float4*>(fm + o11);

    f32x4 o;
    {
        float top, bot;
        top = tl.x + (tr.x - tl.x) * fx; bot = bl.x + (br.x - bl.x) * fx; o.x = top + (bot - top) * fy;
        top = tl.y + (tr.y - tl.y) * fx; bot = bl.y + (br.y - bl.y) * fx; o.y = top + (bot - top) * fy;
        top = tl.z + (tr.z - tl.z) * fx; bot = bl.z + (br.z - bl.z) * fx; o.z = top + (bot - top) * fy;
        top = tl.w + (tr.w - tl.w) * fx; bot = bl.w + (br.w - bl.w) * fx; o.w = top + (bot - top) * fy;
    }

    // Nontemporal streaming store — keep the write-once output stream from
    // evicting the exactly-L2-sized fm slice.
    f32x4* dst = reinterpret_cast<f32x4*>(out + (size_t)cell * FM_C + c4);
    __builtin_nontemporal_store(o, dst);
}

extern "C" void kernel_launch(void* const* d_in, const int* in_sizes, int n_in,
                              void* d_out, int out_size, void* d_ws, size_t ws_size,
                              hipStream_t stream) {
    const float* fm   = (const float*)d_in[0];
    const float* rois = (const float*)d_in[1];
    float* out        = (float*)d_out;

    const int R       = in_sizes[1] / 4;
    const int n_cells = R * POOL * POOL;                       // 1024*49 = 50176
    const int cblocks = (n_cells + CELLS_PER_BLK - 1) / CELLS_PER_BLK;  // 3136
    const int blocks  = cblocks * NGRP;                        // 25088

    roi_pool_kernel<<<blocks, 256, 0, stream>>>(fm, rois, out, n_cells);
}